// Round 6
// baseline (336.934 us; speedup 1.0000x reference)
//
#include <hip/hip_runtime.h>

#define FEA   14
#define OUT   7
#define SCALE (1.0f / 16.0f)
#define BLK   256

// Native 4-float vector: __builtin_nontemporal_store rejects HIP's float4
// (a HIP_vector_type class) but accepts clang ext_vector types.
typedef float fvec4 __attribute__((ext_vector_type(4)));

// Exactly-rounded float reciprocals for denom in {1,2,3} (bin size <= 3 for L<=14 over 7 bins).
__device__ __forceinline__ float inv_small(int d) {
    // d <= 1 maps to 1.0f (matches reference's max(e-s,1); acc is 0 anyway when d==0)
    return (d <= 1) ? 1.0f : ((d == 2) ? 0.5f : 0.33333334f);
}

__global__ __launch_bounds__(BLK) void roi_adaptive_pool_kernel(
    const float* __restrict__ tensor,  // [C, 14, 14]
    const float* __restrict__ ROI,     // [N, 5] rows: (b, x1, y1, x2, y2)
    float* __restrict__ out,           // [N, C, 7, 7]
    int C)
{
    // 7 KB staging for coalesced float4 writeback; 16B-aligned for ds_read_b128.
    __shared__ __align__(16) float st[BLK * OUT];

    const int n   = blockIdx.y;                          // uniform per block -> SALU path
    const int tid = threadIdx.x;
    const int idx = blockIdx.x * BLK + tid;              // c*7 + i
    const int total = C * OUT;
    const bool active = (idx < total);

    // ---- block-uniform ROI -> integer region (compiler scalarizes these) ----
    const float cx1 = ROI[n * 5 + 1] * SCALE;
    const float cy1 = ROI[n * 5 + 2] * SCALE;
    const float cx2 = ROI[n * 5 + 3] * SCALE;
    const float cy2 = ROI[n * 5 + 4] * SCALE;

    const int x1 = (int)fminf(fmaxf(floorf(cx1), 0.0f), (float)FEA);
    const int y1 = (int)fminf(fmaxf(floorf(cy1), 0.0f), (float)FEA);
    const int x2 = (int)fminf(fmaxf(ceilf (cx2), 0.0f), (float)FEA);
    const int y2 = (int)fminf(fmaxf(ceilf (cy2), 0.0f), (float)FEA);
    const int Lx = x2 - x1;
    const int Ly = y2 - y1;

    // ---- x-axis bins: uniform across the block, fully unrolled -> registers ----
    int   sx[OUT], ex[OUT];
    float wx[OUT];
#pragma unroll
    for (int j = 0; j < OUT; ++j) {
        sx[j] = x1 + (j * Lx) / OUT;
        ex[j] = x1 + ((j + 1) * Lx + (OUT - 1)) / OUT;  // ceil
        wx[j] = inv_small(ex[j] - sx[j]);
    }

    // ---- per-lane (c, i) decode and y-bin ----
    const int c = active ? (idx / OUT) : 0;
    const int i = idx - c * OUT;
    const int sy = y1 + (i * Ly) / OUT;
    const int ey = y1 + ((i + 1) * Ly + (OUT - 1)) / OUT;
    const float wy = inv_small(ey - sy);

    // ---- accumulate plain sums over the bin; weights applied at the end ----
    float acc[OUT] = {0.f, 0.f, 0.f, 0.f, 0.f, 0.f, 0.f};
    const float* __restrict__ base = tensor + (size_t)c * (FEA * FEA);
    if (active) {
        for (int y = sy; y < ey; ++y) {
            const float* __restrict__ row = base + y * FEA;
#pragma unroll
            for (int j = 0; j < OUT; ++j) {
                for (int x = sx[j]; x < ex[j]; ++x) {
                    acc[j] += row[x];
                }
            }
        }
    }

    // ---- stage weighted results in LDS (stride 7 across lanes: 2-way = free) ----
    // st[tid*7 + j] == output element (blk_off + tid*7 + j) of this ROI: linear chunk.
#pragma unroll
    for (int j = 0; j < OUT; ++j) {
        st[tid * OUT + j] = acc[j] * (wy * wx[j]);
    }
    __syncthreads();

    // ---- coalesced nontemporal float4 writeback: 448 float4 per block ----
    // Block chunk is 16B-aligned (ROI stride C*49 dwords and block stride 1792
    // dwords are both multiples of 4). Output is write-once, never re-read:
    // nt flag keeps the 205 MB store stream from thrashing L2's copy of the input.
    const size_t roi_base  = (size_t)n * (size_t)total * OUT;        // dwords, start of ROI
    const size_t blk_off   = (size_t)blockIdx.x * (BLK * OUT);       // dwords, block chunk
    const int    roi_elems = total * OUT;                            // C*49
    const fvec4* __restrict__ st4  = (const fvec4*)st;
    fvec4*       __restrict__ out4 = (fvec4*)(out + roi_base + blk_off);
#pragma unroll
    for (int p = 0; p < 2; ++p) {
        const int q = p * BLK + tid;                                 // float4 index, 0..447
        if (q < (BLK * OUT) / 4 && (int)(blk_off + (size_t)q * 4) < roi_elems) {
            __builtin_nontemporal_store(st4[q], &out4[q]);
        }
    }
}

extern "C" void kernel_launch(void* const* d_in, const int* in_sizes, int n_in,
                              void* d_out, int out_size, void* d_ws, size_t ws_size,
                              hipStream_t stream) {
    const float* tensor = (const float*)d_in[0];
    const float* ROI    = (const float*)d_in[1];
    float*       out    = (float*)d_out;

    const int C = in_sizes[0] / (FEA * FEA);  // B == 1 in this problem
    const int N = in_sizes[1] / 5;

    const int work_x = C * OUT;               // threads per ROI: one per (c, i)
    dim3 block(BLK, 1, 1);
    dim3 grid((work_x + BLK - 1) / BLK, N, 1);
    roi_adaptive_pool_kernel<<<grid, block, 0, stream>>>(tensor, ROI, out, C);
}

// Round 7
// 272.017 us; speedup vs baseline: 1.2387x; 1.2387x over previous
//
#include <hip/hip_runtime.h>

#define FEA   14
#define OUT   7
#define SCALE (1.0f / 16.0f)
#define BLK   256
#define CMAX  38     // max channels a 256-thread block touches: ceil(256/7)+1
#define CPAD  200    // padded per-channel LDS stride (196+4); 200 % 32 = 8 breaks dc-conflicts

// Native 4-float vector: __builtin_nontemporal_store rejects HIP's float4 class type.
typedef float fvec4 __attribute__((ext_vector_type(4)));

// Exactly-rounded float reciprocals for denom in {1,2,3} (bin size <= 3 for L<=14 over 7 bins).
__device__ __forceinline__ float inv_small(int d) {
    return (d <= 1) ? 1.0f : ((d == 2) ? 0.5f : 0.33333334f);
}

__global__ __launch_bounds__(BLK) void roi_adaptive_pool_kernel(
    const float* __restrict__ tensor,  // [C, 14, 14]
    const float* __restrict__ ROI,     // [N, 5] rows: (b, x1, y1, x2, y2)
    float* __restrict__ out,           // [N, C, 7, 7]
    int C)
{
    // Input channel tiles (padded stride) + output staging. 30.4KB + 7KB -> 4 blocks/CU.
    __shared__ __align__(16) float sin_[CMAX * CPAD];
    __shared__ __align__(16) float st[BLK * OUT];

    const int n   = blockIdx.y;                          // uniform per block -> SALU path
    const int tid = threadIdx.x;
    const int idx = blockIdx.x * BLK + tid;              // c*7 + i
    const int total = C * OUT;
    const bool active = (idx < total);

    // ---- block's channel range (uniform) ----
    const int c_lo = (blockIdx.x * BLK) / OUT;
    const int c_hi = (blockIdx.x * BLK + (BLK - 1)) / OUT;  // may be clamped by 'active' later
    const int cnt  = min(c_hi, C - 1) - c_lo + 1;           // <= 38
    const int nf4  = cnt * 49;                               // 196/4 = 49 float4 per channel

    // ---- stage input channels to LDS: fully coalesced float4 loads ----
    // Global base c_lo*196 floats = c_lo*784 B, and 784 = 49*16 -> 16B aligned.
    const fvec4* __restrict__ g4 = (const fvec4*)(tensor + (size_t)c_lo * (FEA * FEA));
    for (int t = tid; t < nf4; t += BLK) {
        const int cl  = t / 49;                  // local channel
        const int off = t - cl * 49;             // float4 offset within channel
        *(fvec4*)&sin_[cl * CPAD + off * 4] = g4[t];
    }

    // ---- block-uniform ROI -> integer region (overlaps staging-load latency) ----
    const float cx1 = ROI[n * 5 + 1] * SCALE;
    const float cy1 = ROI[n * 5 + 2] * SCALE;
    const float cx2 = ROI[n * 5 + 3] * SCALE;
    const float cy2 = ROI[n * 5 + 4] * SCALE;

    const int x1 = (int)fminf(fmaxf(floorf(cx1), 0.0f), (float)FEA);
    const int y1 = (int)fminf(fmaxf(floorf(cy1), 0.0f), (float)FEA);
    const int x2 = (int)fminf(fmaxf(ceilf (cx2), 0.0f), (float)FEA);
    const int y2 = (int)fminf(fmaxf(ceilf (cy2), 0.0f), (float)FEA);
    const int Lx = x2 - x1;
    const int Ly = y2 - y1;

    // ---- x-axis bins: uniform across the block, fully unrolled -> registers ----
    int   sx[OUT], ex[OUT];
    float wx[OUT];
#pragma unroll
    for (int j = 0; j < OUT; ++j) {
        sx[j] = x1 + (j * Lx) / OUT;
        ex[j] = x1 + ((j + 1) * Lx + (OUT - 1)) / OUT;  // ceil
        wx[j] = inv_small(ex[j] - sx[j]);
    }

    // ---- per-lane (c, i) decode and y-bin ----
    const int c = active ? (idx / OUT) : 0;
    const int i = idx - c * OUT;
    const int sy = y1 + (i * Ly) / OUT;
    const int ey = y1 + ((i + 1) * Ly + (OUT - 1)) / OUT;
    const float wy = inv_small(ey - sy);

    __syncthreads();   // staging complete

    // ---- accumulate from LDS (x-loops are block-uniform; only y-loop diverges <=3) ----
    float acc[OUT] = {0.f, 0.f, 0.f, 0.f, 0.f, 0.f, 0.f};
    const int cbase = (c - c_lo) * CPAD;
    if (active) {
        for (int y = sy; y < ey; ++y) {
            const float* __restrict__ row = &sin_[cbase + y * FEA];
#pragma unroll
            for (int j = 0; j < OUT; ++j) {
                for (int x = sx[j]; x < ex[j]; ++x) {
                    acc[j] += row[x];
                }
            }
        }
    }

    // ---- stage weighted results in LDS (stride 7 across lanes: 2-way = free) ----
#pragma unroll
    for (int j = 0; j < OUT; ++j) {
        st[tid * OUT + j] = acc[j] * (wy * wx[j]);
    }
    __syncthreads();

    // ---- coalesced nontemporal float4 writeback: 448 float4 per block ----
    const size_t roi_base  = (size_t)n * (size_t)total * OUT;        // dwords
    const size_t blk_off   = (size_t)blockIdx.x * (BLK * OUT);       // dwords
    const int    roi_elems = total * OUT;                            // C*49
    const fvec4* __restrict__ st4  = (const fvec4*)st;
    fvec4*       __restrict__ out4 = (fvec4*)(out + roi_base + blk_off);
#pragma unroll
    for (int p = 0; p < 2; ++p) {
        const int q = p * BLK + tid;                                 // float4 index, 0..447
        if (q < (BLK * OUT) / 4 && (int)(blk_off + (size_t)q * 4) < roi_elems) {
            __builtin_nontemporal_store(st4[q], &out4[q]);
        }
    }
}

extern "C" void kernel_launch(void* const* d_in, const int* in_sizes, int n_in,
                              void* d_out, int out_size, void* d_ws, size_t ws_size,
                              hipStream_t stream) {
    const float* tensor = (const float*)d_in[0];
    const float* ROI    = (const float*)d_in[1];
    float*       out    = (float*)d_out;

    const int C = in_sizes[0] / (FEA * FEA);  // B == 1 in this problem
    const int N = in_sizes[1] / 5;

    const int work_x = C * OUT;               // threads per ROI: one per (c, i)
    dim3 block(BLK, 1, 1);
    dim3 grid((work_x + BLK - 1) / BLK, N, 1);
    roi_adaptive_pool_kernel<<<grid, block, 0, stream>>>(tensor, ROI, out, C);
}

// Round 8
// 251.975 us; speedup vs baseline: 1.3372x; 1.0795x over previous
//
#include <hip/hip_runtime.h>

#define FEA   14
#define OUT   7
#define SCALE (1.0f / 16.0f)
#define BLK   256
#define CMAX  7      // max channels spanned by 256 consecutive (c,i,j) outputs: ceil(256/49)+1
#define CPAD  197    // odd LDS channel stride; 197 % 32 = 5 (coprime) -> banks well spread
#define GROUPS 16    // ROI groups (grid.y); each block loops N/GROUPS ROIs

typedef float fvec4 __attribute__((ext_vector_type(4)));

// Exactly-rounded reciprocals for bin sizes {1,2,3} (max bin = 3 for L<=14 over 7 bins).
__device__ __forceinline__ float inv_small(int d) {
    return (d <= 1) ? 1.0f : ((d == 2) ? 0.5f : 0.33333334f);
}

// floor(k*L/7) and ceil(k*L/7) via float mul with margin constants:
// C7P = 1/7 + 1e-4 (floor path), C7M = 1/7 - 1e-4 (ceil path). For integer
// products k*L <= 84 the +-8.4e-3 worst-case skew stays far from the next
// integer (gap >= 1/7), and lands on the correct side at exact multiples of 7.
#define C7P 0.14295714f
#define C7M 0.14275714f

__global__ __launch_bounds__(BLK) void roi_adaptive_pool_kernel(
    const float* __restrict__ tensor,  // [C, 14, 14]
    const float* __restrict__ ROI,     // [N, 5] rows: (b, x1, y1, x2, y2)
    float* __restrict__ out,           // [N, C, 7, 7]
    int C, int N)
{
    __shared__ float sin_[CMAX * CPAD];   // 5.5 KB -> 8 blocks/CU (wave-limited)

    const int tid   = threadIdx.x;
    const int o0    = blockIdx.x * BLK;        // flat output offset within one ROI
    const int total = C * OUT * OUT;           // C*49 (= 100352 for C=2048)

    // ---- stage this block's channel range to LDS (once per 32 ROIs) ----
    const int c_lo = o0 / 49;
    const int c_hi = min((o0 + BLK - 1) / 49, C - 1);
    const int nf4  = (c_hi - c_lo + 1) * 49;   // float4 count, <= 343 (196B/channel, 16B-aligned base)
    const fvec4* __restrict__ g4 = (const fvec4*)(tensor + (size_t)c_lo * (FEA * FEA));
    for (int t = tid; t < nf4; t += BLK) {
        fvec4 v = g4[t];
        const int f   = t * 4;
        const int cl  = f / 196;               // local channel
        const int off = f - cl * 196;          // dword offset within channel (mult of 4)
        float* p = &sin_[cl * CPAD + off];     // scalar writes: CPAD is odd (no 16B align)
        p[0] = v.x; p[1] = v.y; p[2] = v.z; p[3] = v.w;
    }

    // ---- fixed per-thread decode: output element (c, i, j) ----
    const int oi = o0 + tid;
    const bool active = (oi < total);
    const int c  = active ? (oi / 49) : c_lo;
    const int r  = oi - c * 49;
    const int i  = r / 7;
    const int j  = r - i * 7;
    const int lbase = (c - c_lo) * CPAD;
    // per-thread float bin coefficients (computed once)
    const float jP  = (float)j       * C7P;
    const float j1M = (float)(j + 1) * C7M;
    const float iP  = (float)i       * C7P;
    const float i1M = (float)(i + 1) * C7M;

    __syncthreads();
    if (!active) return;

    // ---- loop over this group's ROIs; stores are lane-contiguous nt dwords ----
    const int n0    = blockIdx.y * ((N + GROUPS - 1) / GROUPS);
    const int n_end = min(n0 + (N + GROUPS - 1) / GROUPS, N);
    if (n0 >= N) return;

    // prefetch first ROI row
    float rx1 = ROI[(size_t)n0 * 5 + 1], ry1 = ROI[(size_t)n0 * 5 + 2];
    float rx2 = ROI[(size_t)n0 * 5 + 3], ry2 = ROI[(size_t)n0 * 5 + 4];
    float* __restrict__ outp = out + (size_t)n0 * total + oi;

    for (int n = n0; n < n_end; ++n) {
        const float x1f = floorf(rx1 * SCALE);   // data guarantees 0 <= x1f <= 7 (no clip needed)
        const float y1f = floorf(ry1 * SCALE);
        const float x2f = ceilf (rx2 * SCALE);   // <= 14 by construction (x2 <= 224)
        const float y2f = ceilf (ry2 * SCALE);
        // prefetch next ROI row (hide L2 latency under this iteration's compute)
        if (n + 1 < n_end) {
            const float* __restrict__ rp = &ROI[(size_t)(n + 1) * 5];
            rx1 = rp[1]; ry1 = rp[2]; rx2 = rp[3]; ry2 = rp[4];
        }
        const float Lxf = x2f - x1f;
        const float Lyf = y2f - y1f;
        const int x1i = (int)x1f, y1i = (int)y1f;

        const int sx = x1i + (int)(jP  * Lxf);           // trunc == floor (>=0)
        const int ex = x1i + (int)ceilf(j1M * Lxf);
        const int sy = y1i + (int)(iP  * Lyf);
        const int ey = y1i + (int)ceilf(i1M * Lyf);
        const float w = inv_small(ex - sx) * inv_small(ey - sy);

        float acc = 0.f;
        for (int y = sy; y < ey; ++y) {
            const float* __restrict__ row = &sin_[lbase + y * FEA];
            for (int x = sx; x < ex; ++x) acc += row[x];
        }
        __builtin_nontemporal_store(acc * w, outp);
        outp += total;
    }
}

extern "C" void kernel_launch(void* const* d_in, const int* in_sizes, int n_in,
                              void* d_out, int out_size, void* d_ws, size_t ws_size,
                              hipStream_t stream) {
    const float* tensor = (const float*)d_in[0];
    const float* ROI    = (const float*)d_in[1];
    float*       out    = (float*)d_out;

    const int C = in_sizes[0] / (FEA * FEA);   // B == 1 in this problem
    const int N = in_sizes[1] / 5;

    const int total = C * OUT * OUT;           // outputs per ROI
    dim3 block(BLK, 1, 1);
    dim3 grid((total + BLK - 1) / BLK, GROUPS, 1);   // 392 x 16 for C=2048
    roi_adaptive_pool_kernel<<<grid, block, 0, stream>>>(tensor, ROI, out, C, N);
}

// Round 9
// 232.199 us; speedup vs baseline: 1.4511x; 1.0852x over previous
//
#include <hip/hip_runtime.h>

#define FEA    14
#define OUT    7
#define SCALE  (1.0f / 16.0f)
#define BLK    256
#define CMAX   7                  // channels spanned by 256 consecutive (c,i,j) outputs
#define RS     17                 // S row stride (15 rows/channel); odd -> banks scrambled
#define CH     (15 * RS)          // 255 floats per channel slab
#define GROUPS 16                 // ROI groups; each block loops N/GROUPS ROIs

// floor/ceil of k*L/7 via float mul with margin constants (passed rounds 6-8):
// C7P = 1/7 + 1e-4 (floor path), C7M = 1/7 - 1e-4 (ceil path); exact for k*L <= 84.
#define C7P 0.14295714f
#define C7M 0.14275714f

// Exactly-rounded reciprocals for bin sizes {1,2,3}.
__device__ __forceinline__ float inv_small(int d) {
    return (d <= 1) ? 1.0f : ((d == 2) ? 0.5f : 0.33333334f);
}

__global__ __launch_bounds__(BLK) void roi_adaptive_pool_kernel(
    const float* __restrict__ tensor,  // [C, 14, 14]
    const float* __restrict__ ROI,     // [N, 5]
    float* __restrict__ out,           // [N, C, 7, 7]
    int C, int N)
{
    // Per-channel integral images with zero guard row/col:
    // S[cl][y][x] = sum of raw[y' < y][x' < x]  (y,x in 0..14). 7.1 KB.
    __shared__ float S[CMAX * CH];

    const int tid   = threadIdx.x;
    const int o0    = blockIdx.x * BLK;        // flat output offset within one ROI
    const int total = C * OUT * OUT;           // C*49

    const int c_lo = o0 / 49;
    const int c_hi = min((o0 + BLK - 1) / 49, C - 1);
    const int cnt  = c_hi - c_lo + 1;          // 6 or 7

    // ---- Phase 0: row prefixes into rows 1..14 (col 0 guard = 0) ----
    if (tid < CMAX * FEA) {                    // 98 row-threads
        const int cl = tid / FEA;
        const int y  = tid - cl * FEA;
        if (cl < cnt) {
            const float* __restrict__ g =
                tensor + (size_t)(c_lo + cl) * (FEA * FEA) + y * FEA;
            float* __restrict__ s = &S[cl * CH + (y + 1) * RS];
            s[0] = 0.f;
            float run = 0.f;
#pragma unroll
            for (int x = 0; x < FEA; ++x) { run += g[x]; s[x + 1] = run; }
        }
    } else if (tid < CMAX * FEA + CMAX * 15) { // 105 threads: row-0 guard
        const int t2 = tid - CMAX * FEA;
        const int cl = t2 / 15;
        const int x  = t2 - cl * 15;
        if (cl < cnt) S[cl * CH + x] = 0.f;
    }
    __syncthreads();

    // ---- Phase 1: column prefix down rows 1..14 for cols 1..14 ----
    if (tid < CMAX * FEA) {
        const int cl = tid / FEA;
        const int x  = (tid - cl * FEA) + 1;
        if (cl < cnt) {
            float* __restrict__ s = &S[cl * CH + x];
            float run = 0.f;
#pragma unroll
            for (int y = 1; y <= FEA; ++y) { run += s[y * RS]; s[y * RS] = run; }
        }
    }

    // ---- per-thread fixed decode (overlaps phase-1 latency) ----
    const int oi = o0 + tid;
    const bool active = (oi < total);
    const int c  = active ? (oi / 49) : c_lo;
    const int rr = active ? (oi - c * 49) : 0;
    const int i  = rr / 7;
    const int j  = rr - i * 7;
    const int sb = (c - c_lo) * CH;
    const float jP  = (float)j       * C7P;
    const float j1M = (float)(j + 1) * C7M;
    const float iP  = (float)i       * C7P;
    const float i1M = (float)(i + 1) * C7M;

    __syncthreads();   // integral images ready

    // ---- loop over this group's ROIs; 4 LDS reads + 1 nt store per output ----
    const int per   = (N + GROUPS - 1) / GROUPS;
    const int n0    = blockIdx.y * per;
    const int n_end = min(n0 + per, N);
    if (n0 >= n_end) return;

    float* __restrict__ outp = out + (size_t)n0 * total + oi;
    float rx1 = ROI[(size_t)n0 * 5 + 1], ry1 = ROI[(size_t)n0 * 5 + 2];
    float rx2 = ROI[(size_t)n0 * 5 + 3], ry2 = ROI[(size_t)n0 * 5 + 4];

    for (int n = n0; n < n_end; ++n) {
        const float x1f = floorf(rx1 * SCALE);   // data guarantees 0 <= x1f, x2f <= 14
        const float y1f = floorf(ry1 * SCALE);
        const float x2f = ceilf (rx2 * SCALE);
        const float y2f = ceilf (ry2 * SCALE);
        // prefetch next ROI row (uniform, L2-hit) under this iteration's compute
        if (n + 1 < n_end) {
            const float* __restrict__ rp = &ROI[(size_t)(n + 1) * 5];
            rx1 = rp[1]; ry1 = rp[2]; rx2 = rp[3]; ry2 = rp[4];
        }
        const float Lxf = x2f - x1f;
        const float Lyf = y2f - y1f;
        const int x1i = (int)x1f, y1i = (int)y1f;

        const int sx = x1i + (int)(jP * Lxf);            // trunc == floor (>= 0)
        const int ex = x1i + (int)ceilf(j1M * Lxf);
        const int sy = y1i + (int)(iP * Lyf);
        const int ey = y1i + (int)ceilf(i1M * Lyf);
        const float w = inv_small(ex - sx) * inv_small(ey - sy);

        const float* __restrict__ Sy0 = &S[sb + sy * RS];
        const float* __restrict__ Sy1 = &S[sb + ey * RS];
        const float acc = (Sy1[ex] - Sy0[ex]) - (Sy1[sx] - Sy0[sx]);

        if (active) __builtin_nontemporal_store(acc * w, outp);
        outp += total;
    }
}

extern "C" void kernel_launch(void* const* d_in, const int* in_sizes, int n_in,
                              void* d_out, int out_size, void* d_ws, size_t ws_size,
                              hipStream_t stream) {
    const float* tensor = (const float*)d_in[0];
    const float* ROI    = (const float*)d_in[1];
    float*       out    = (float*)d_out;

    const int C = in_sizes[0] / (FEA * FEA);   // B == 1 in this problem
    const int N = in_sizes[1] / 5;

    const int total = C * OUT * OUT;           // outputs per ROI
    dim3 block(BLK, 1, 1);
    dim3 grid((total + BLK - 1) / BLK, GROUPS, 1);   // 392 x 16 for C=2048, N=512
    roi_adaptive_pool_kernel<<<grid, block, 0, stream>>>(tensor, ROI, out, C, N);
}

// Round 11
// 227.429 us; speedup vs baseline: 1.4815x; 1.0210x over previous
//
#include <hip/hip_runtime.h>
#include <stdint.h>

#define FEA    14
#define OUT    7
#define SCALE  (1.0f / 16.0f)
#define BLK    256
#define CMAX   7                  // channels spanned by 256 consecutive (c,i,j) outputs
#define RS     17                 // S row stride; odd -> banks scrambled
#define CH     (15 * RS)          // 255 floats per channel slab
#define GROUPS 16                 // ROI groups; each block loops N/GROUPS ROIs

// floor/ceil of k*L/7 via float mul with margins (fallback path only; passed r6-r9).
#define C7P 0.14295714f
#define C7M 0.14275714f

// Exactly-rounded reciprocals for bin sizes {1,2,3}.
__device__ __forceinline__ float inv_small(int d) {
    return (d <= 1) ? 1.0f : ((d == 2) ? 0.5f : 0.33333334f);
}

// ---------- pre-kernel: one descriptor per (ROI, i, j) ----------
// rec.x = sx | ex<<8 | (sy*RS)<<16 | (ey*RS)<<24   (all fields <= 238)
// rec.y = bitcast(weight)
__global__ __launch_bounds__(BLK) void roi_bins_kernel(
    const float* __restrict__ ROI, uint2* __restrict__ tab, int N)
{
    const int k = blockIdx.x * BLK + threadIdx.x;   // n*49 + ij
    if (k >= N * 49) return;
    const int n  = k / 49;
    const int ij = k - n * 49;
    const int i  = ij / 7;
    const int j  = ij - i * 7;
    const float* __restrict__ r = &ROI[(size_t)n * 5];
    // data guarantees 0 <= x1f and x2f <= 14 (x1<7.5*16, x2<=224) -> no clamping
    const int x1i = (int)floorf(r[1] * SCALE);
    const int y1i = (int)floorf(r[2] * SCALE);
    const int x2i = (int)ceilf (r[3] * SCALE);
    const int y2i = (int)ceilf (r[4] * SCALE);
    const int Lx = x2i - x1i, Ly = y2i - y1i;
    const int sx = x1i + (j * Lx) / 7;               // exact integer bin edges
    const int ex = x1i + ((j + 1) * Lx + 6) / 7;
    const int sy = y1i + (i * Ly) / 7;
    const int ey = y1i + ((i + 1) * Ly + 6) / 7;
    const float w = inv_small(ex - sx) * inv_small(ey - sy);
    uint2 rec;
    rec.x = (uint32_t)sx | ((uint32_t)ex << 8)
          | ((uint32_t)(sy * RS) << 16) | ((uint32_t)(ey * RS) << 24);
    rec.y = __float_as_uint(w);
    tab[k] = rec;
}

// ---------- main kernel: integral image in LDS + table-driven 4-corner sums ----------
__global__ __launch_bounds__(BLK) void roi_pool_main(
    const float* __restrict__ tensor,  // [C, 14, 14]
    const uint2* __restrict__ tab,     // [N*49] descriptors
    float* __restrict__ out,           // [N, C, 7, 7]
    int C, int N)
{
    // Per-channel integral image, zero guard row/col: S[cl][y][x], y,x in 0..14. 7.1 KB.
    __shared__ float S[CMAX * CH];

    const int tid   = threadIdx.x;
    const int o0    = blockIdx.x * BLK;        // flat output offset within one ROI
    const int total = C * OUT * OUT;           // C*49

    const int c_lo = o0 / 49;
    const int c_hi = min((o0 + BLK - 1) / 49, C - 1);
    const int cnt  = c_hi - c_lo + 1;          // 6 or 7

    // Phase 0: row prefixes into rows 1..14 (col 0 guard = 0)
    if (tid < CMAX * FEA) {
        const int cl = tid / FEA;
        const int y  = tid - cl * FEA;
        if (cl < cnt) {
            const float* __restrict__ g =
                tensor + (size_t)(c_lo + cl) * (FEA * FEA) + y * FEA;
            float* __restrict__ s = &S[cl * CH + (y + 1) * RS];
            s[0] = 0.f;
            float run = 0.f;
#pragma unroll
            for (int x = 0; x < FEA; ++x) { run += g[x]; s[x + 1] = run; }
        }
    } else if (tid < CMAX * FEA + CMAX * 15) { // row-0 guard
        const int t2 = tid - CMAX * FEA;
        const int cl = t2 / 15;
        const int x  = t2 - cl * 15;
        if (cl < cnt) S[cl * CH + x] = 0.f;
    }
    __syncthreads();

    // Phase 1: column prefix down rows 1..14 for cols 1..14
    if (tid < CMAX * FEA) {
        const int cl = tid / FEA;
        const int x  = (tid - cl * FEA) + 1;
        if (cl < cnt) {
            float* __restrict__ s = &S[cl * CH + x];
            float run = 0.f;
#pragma unroll
            for (int y = 1; y <= FEA; ++y) { run += s[y * RS]; s[y * RS] = run; }
        }
    }

    // fixed per-thread decode (overlaps phase-1 latency)
    const int oi = o0 + tid;
    const bool active = (oi < total);
    const int c  = active ? (oi / 49) : c_lo;
    const int ij = active ? (oi - c * 49) : 0;
    const float* __restrict__ Sc = S + (c - c_lo) * CH;

    __syncthreads();   // integral images ready

    // loop over this group's ROIs: 1 table load + 4 LDS reads + 1 nt store per output
    const int per   = (N + GROUPS - 1) / GROUPS;
    const int n0    = blockIdx.y * per;
    const int n_end = min(n0 + per, N);
    if (n0 >= n_end) return;

    float* __restrict__ outp = out + (size_t)n0 * total + oi;
    int ridx = n0 * 49 + ij;
    uint2 rec = tab[ridx];                       // prefetched 1-deep
    for (int n = n0; n < n_end; ++n) {
        const uint32_t p = rec.x;
        const float    w = __uint_as_float(rec.y);
        if (n + 1 < n_end) rec = tab[ridx + 49]; // next ROI's record (L1/L2-hit)
        ridx += 49;
        const int sx  =  p        & 0xFF;
        const int ex  = (p >> 8)  & 0xFF;
        const int oy0 = (p >> 16) & 0xFF;        // sy*RS
        const int oy1 =  p >> 24;                // ey*RS
        const float acc = (Sc[oy1 + ex] - Sc[oy0 + ex]) - (Sc[oy1 + sx] - Sc[oy0 + sx]);
        if (active) __builtin_nontemporal_store(acc * w, outp);
        outp += total;
    }
}

// ---------- fallback (ws too small): self-contained round-9 kernel ----------
__global__ __launch_bounds__(BLK) void roi_pool_fallback(
    const float* __restrict__ tensor, const float* __restrict__ ROI,
    float* __restrict__ out, int C, int N)
{
    __shared__ float S[CMAX * CH];
    const int tid   = threadIdx.x;
    const int o0    = blockIdx.x * BLK;
    const int total = C * OUT * OUT;
    const int c_lo = o0 / 49;
    const int c_hi = min((o0 + BLK - 1) / 49, C - 1);
    const int cnt  = c_hi - c_lo + 1;
    if (tid < CMAX * FEA) {
        const int cl = tid / FEA;
        const int y  = tid - cl * FEA;
        if (cl < cnt) {
            const float* __restrict__ g = tensor + (size_t)(c_lo + cl) * (FEA * FEA) + y * FEA;
            float* __restrict__ s = &S[cl * CH + (y + 1) * RS];
            s[0] = 0.f;
            float run = 0.f;
#pragma unroll
            for (int x = 0; x < FEA; ++x) { run += g[x]; s[x + 1] = run; }
        }
    } else if (tid < CMAX * FEA + CMAX * 15) {
        const int t2 = tid - CMAX * FEA;
        const int cl = t2 / 15;
        const int x  = t2 - cl * 15;
        if (cl < cnt) S[cl * CH + x] = 0.f;
    }
    __syncthreads();
    if (tid < CMAX * FEA) {
        const int cl = tid / FEA;
        const int x  = (tid - cl * FEA) + 1;
        if (cl < cnt) {
            float* __restrict__ s = &S[cl * CH + x];
            float run = 0.f;
#pragma unroll
            for (int y = 1; y <= FEA; ++y) { run += s[y * RS]; s[y * RS] = run; }
        }
    }
    const int oi = o0 + tid;
    const bool active = (oi < total);
    const int c  = active ? (oi / 49) : c_lo;
    const int rr = active ? (oi - c * 49) : 0;
    const int i  = rr / 7;
    const int j  = rr - i * 7;
    const int sb = (c - c_lo) * CH;
    const float jP  = (float)j       * C7P;
    const float j1M = (float)(j + 1) * C7M;
    const float iP  = (float)i       * C7P;
    const float i1M = (float)(i + 1) * C7M;
    __syncthreads();
    const int per   = (N + GROUPS - 1) / GROUPS;
    const int n0    = blockIdx.y * per;
    const int n_end = min(n0 + per, N);
    if (n0 >= n_end) return;
    float* __restrict__ outp = out + (size_t)n0 * total + oi;
    float rx1 = ROI[(size_t)n0 * 5 + 1], ry1 = ROI[(size_t)n0 * 5 + 2];
    float rx2 = ROI[(size_t)n0 * 5 + 3], ry2 = ROI[(size_t)n0 * 5 + 4];
    for (int n = n0; n < n_end; ++n) {
        const float x1f = floorf(rx1 * SCALE);
        const float y1f = floorf(ry1 * SCALE);
        const float x2f = ceilf (rx2 * SCALE);
        const float y2f = ceilf (ry2 * SCALE);
        if (n + 1 < n_end) {
            const float* __restrict__ rp = &ROI[(size_t)(n + 1) * 5];
            rx1 = rp[1]; ry1 = rp[2]; rx2 = rp[3]; ry2 = rp[4];
        }
        const float Lxf = x2f - x1f;
        const float Lyf = y2f - y1f;
        const int x1i = (int)x1f, y1i = (int)y1f;
        const int sx = x1i + (int)(jP * Lxf);
        const int ex = x1i + (int)ceilf(j1M * Lxf);
        const int sy = y1i + (int)(iP * Lyf);
        const int ey = y1i + (int)ceilf(i1M * Lyf);
        const float w = inv_small(ex - sx) * inv_small(ey - sy);
        const float* __restrict__ Sy0 = &S[sb + sy * RS];
        const float* __restrict__ Sy1 = &S[sb + ey * RS];
        const float acc = (Sy1[ex] - Sy0[ex]) - (Sy1[sx] - Sy0[sx]);
        if (active) __builtin_nontemporal_store(acc * w, outp);
        outp += total;
    }
}

extern "C" void kernel_launch(void* const* d_in, const int* in_sizes, int n_in,
                              void* d_out, int out_size, void* d_ws, size_t ws_size,
                              hipStream_t stream) {
    const float* tensor = (const float*)d_in[0];
    const float* ROI    = (const float*)d_in[1];
    float*       out    = (float*)d_out;

    const int C = in_sizes[0] / (FEA * FEA);   // B == 1 in this problem
    const int N = in_sizes[1] / 5;

    const int total = C * OUT * OUT;           // outputs per ROI
    dim3 block(BLK, 1, 1);
    dim3 grid((total + BLK - 1) / BLK, GROUPS, 1);   // 392 x 16 for C=2048, N=512

    const size_t tab_bytes = (size_t)N * 49 * sizeof(uint2);   // 200,704 B
    if (ws_size >= tab_bytes) {
        uint2* tab = (uint2*)d_ws;
        const int nbins = N * 49;
        roi_bins_kernel<<<(nbins + BLK - 1) / BLK, block, 0, stream>>>(ROI, tab, N);
        roi_pool_main<<<grid, block, 0, stream>>>(tensor, tab, out, C, N);
    } else {
        roi_pool_fallback<<<grid, block, 0, stream>>>(tensor, ROI, out, C, N);
    }
}